// Round 7
// baseline (111.355 us; speedup 1.0000x reference)
//
#include <hip/hip_runtime.h>
#include <math.h>

#define BINS 10
#define BLOCK 256
#define NBLOCKS_MAX 2048

// ---------------------------------------------------------------------------
// Pass 1: one sweep. Fast transcendentals for sigmoid/log1p; histogram via
// per-thread-column LDS atomics: addr = bi*BLOCK + tid -> bank = tid%32,
// conflict-free for ANY bin value, no address sharing between lanes.
// Replaces the 10-way predicated register update (~36 VALU slots/elem)
// with ~3 VALU + 2 DS-pipe ops.
// ---------------------------------------------------------------------------

__device__ __forceinline__ void proc_elem(float xv, float tv, int tid,
                                          float* __restrict__ sum_lds,
                                          unsigned int* __restrict__ cnt_lds) {
    const float L2E = 1.44269504088896f;   // log2(e)
    const float LN2 = 0.69314718055995f;   // ln(2)
    float e   = __builtin_amdgcn_exp2f(-L2E * __builtin_fabsf(xv)); // exp(-|x|)
    float ope = 1.0f + e;
    float r   = __builtin_amdgcn_rcpf(ope);            // 1/(1+e)
    float sig = (xv >= 0.0f) ? r : e * r;              // stable sigmoid
    float g   = __builtin_fabsf(sig - tv);             // in [0,1]
    int bi = (int)(g * 9.9999f);                       // floor; g<=1 -> bi<=9
    bi = bi > (BINS - 1) ? (BINS - 1) : bi;            // LDS-safety clamp
    float l2  = __builtin_amdgcn_logf(ope);            // log2(1+e)
    float bce = __builtin_fmaf(-xv, tv, __builtin_fmaxf(xv, 0.0f));
    bce = __builtin_fmaf(LN2, l2, bce);                // + ln(1+e)
    int idx = bi * BLOCK + tid;
    atomicAdd(&sum_lds[idx], bce);                     // ds_add_f32, no conflict
    atomicAdd(&cnt_lds[idx], 1u);                      // ds_add_u32, same vaddr
}

__global__ __launch_bounds__(BLOCK) void ghm_pass1(
        const float4* __restrict__ x4, const float4* __restrict__ t4,
        const float* __restrict__ x, const float* __restrict__ t,
        float* __restrict__ psum, unsigned int* __restrict__ pcnt,
        int nvec, int total) {
    __shared__ float        sum_lds[BINS * BLOCK];     // 10 KiB
    __shared__ unsigned int cnt_lds[BINS * BLOCK];     // 10 KiB  -> 20 KiB tot
    const int tid = threadIdx.x;

#pragma unroll
    for (int b = 0; b < BINS; ++b) {
        sum_lds[b * BLOCK + tid] = 0.0f;
        cnt_lds[b * BLOCK + tid] = 0u;
    }
    __syncthreads();

    const int stride = gridDim.x * blockDim.x;
    const int gid0   = blockIdx.x * BLOCK + tid;

    for (int i = gid0; i < nvec; i += stride) {
        float4 xv = x4[i];
        float4 tv = t4[i];
        proc_elem(xv.x, tv.x, tid, sum_lds, cnt_lds);
        proc_elem(xv.y, tv.y, tid, sum_lds, cnt_lds);
        proc_elem(xv.z, tv.z, tid, sum_lds, cnt_lds);
        proc_elem(xv.w, tv.w, tid, sum_lds, cnt_lds);
    }
    // scalar tail (not hit for this shape; kept for safety)
    for (int j = nvec * 4 + gid0; j < total; j += stride)
        proc_elem(x[j], t[j], tid, sum_lds, cnt_lds);

    __syncthreads();

    // read own columns, then reuse the SAME LDS for cross-wave partials
    float        sv[BINS];
    unsigned int cv[BINS];
#pragma unroll
    for (int b = 0; b < BINS; ++b) {
        sv[b] = sum_lds[b * BLOCK + tid];
        cv[b] = cnt_lds[b * BLOCK + tid];
    }
    __syncthreads();                                   // reads done -> reuse ok

    const int lane = tid & 63;
    const int wid  = tid >> 6;
#pragma unroll
    for (int b = 0; b < BINS; ++b) {
        float        s = sv[b];
        unsigned int c = cv[b];
#pragma unroll
        for (int off = 32; off > 0; off >>= 1) {
            s += __shfl_down(s, off);
            c += __shfl_down(c, off);
        }
        if (lane == 0) { sum_lds[wid * BINS + b] = s; cnt_lds[wid * BINS + b] = c; }
    }
    __syncthreads();
    if (tid < BINS) {
        float        s = 0.0f;
        unsigned int c = 0u;
#pragma unroll
        for (int w = 0; w < BLOCK / 64; ++w) {
            s += sum_lds[w * BINS + tid];
            c += cnt_lds[w * BINS + tid];
        }
        psum[(size_t)blockIdx.x * BINS + tid] = s;
        pcnt[(size_t)blockIdx.x * BINS + tid] = c;
    }
}

// ---------------------------------------------------------------------------
// Pass 2: single strided sweep over partials (10 static accumulators per
// thread), one wave+LDS reduce, beta math as in the reference (fp32).
// ---------------------------------------------------------------------------

__global__ __launch_bounds__(BLOCK) void ghm_pass2(
        const float* __restrict__ psum, const unsigned int* __restrict__ pcnt,
        float* __restrict__ out, int nblocks, float Nf, double inv_total) {
    double       s[BINS];
    unsigned int c[BINS];
#pragma unroll
    for (int b = 0; b < BINS; ++b) { s[b] = 0.0; c[b] = 0u; }

    for (int i = threadIdx.x; i < nblocks; i += BLOCK) {
#pragma unroll
        for (int b = 0; b < BINS; ++b) {
            s[b] += (double)psum[(size_t)i * BINS + b];
            c[b] += pcnt[(size_t)i * BINS + b];
        }
    }

    __shared__ double       ls[BLOCK / 64][BINS];
    __shared__ unsigned int lc[BLOCK / 64][BINS];
    const int lane = threadIdx.x & 63;
    const int wid  = threadIdx.x >> 6;
#pragma unroll
    for (int b = 0; b < BINS; ++b) {
        double       sb = s[b];
        unsigned int cb = c[b];
#pragma unroll
        for (int off = 32; off > 0; off >>= 1) {
            sb += __shfl_down(sb, off);
            cb += __shfl_down(cb, off);
        }
        if (lane == 0) { ls[wid][b] = sb; lc[wid][b] = cb; }
    }
    __syncthreads();

    if (threadIdx.x == 0) {
        double             bin_sum[BINS];
        unsigned long long bin_cnt[BINS];
#pragma unroll
        for (int b = 0; b < BINS; ++b) {
            double ts = 0.0;
            unsigned long long tc = 0;
#pragma unroll
            for (int w = 0; w < BLOCK / 64; ++w) { ts += ls[w][b]; tc += lc[w][b]; }
            bin_sum[b] = ts;
            bin_cnt[b] = tc;
        }
        float nonempty = 0.0f;
#pragma unroll
        for (int b = 0; b < BINS; ++b) nonempty += (bin_cnt[b] > 0) ? 1.0f : 0.0f;
        double acc = 0.0;
#pragma unroll
        for (int b = 0; b < BINS; ++b) {
            float bc   = (float)bin_cnt[b];            // reference keeps fp32
            float gd   = fmaxf(bc * nonempty, 1e-6f);
            float beta = Nf / gd;
            acc += (double)beta * bin_sum[b];
        }
        out[0] = (float)(acc * inv_total);
    }
}

// ---------------------------------------------------------------------------

extern "C" void kernel_launch(void* const* d_in, const int* in_sizes, int n_in,
                              void* d_out, int out_size, void* d_ws, size_t ws_size,
                              hipStream_t stream) {
    const float* x = (const float*)d_in[0];
    const float* t = (const float*)d_in[1];
    const int total = in_sizes[0];          // 1048576 * 16
    const int nvec  = total / 4;
    const int N     = total / 16;           // x.shape[0] (first dim)

    int nblocks = NBLOCKS_MAX;
    size_t per_block = (size_t)BINS * (sizeof(float) + sizeof(unsigned int));
    if ((size_t)nblocks * per_block > ws_size) {
        nblocks = (int)(ws_size / per_block);
        if (nblocks < 1) nblocks = 1;
    }

    float*        psum = (float*)d_ws;
    unsigned int* pcnt = (unsigned int*)((char*)d_ws +
                          (size_t)nblocks * BINS * sizeof(float));

    ghm_pass1<<<nblocks, BLOCK, 0, stream>>>(
        (const float4*)x, (const float4*)t, x, t, psum, pcnt, nvec, total);
    ghm_pass2<<<1, BLOCK, 0, stream>>>(
        psum, pcnt, (float*)d_out, nblocks, (float)N, 1.0 / (double)total);
}

// Round 8
// 52.131 us; speedup vs baseline: 2.1361x; 2.1361x over previous
//
#include <hip/hip_runtime.h>
#include <math.h>

#define BINS 10
#define BLOCK 256
#define NBLK 4096

// ---------------------------------------------------------------------------
// Pass 1: one sweep. Fast transcendentals; histogram via ONE native integer
// LDS atomic per element: u64 = (count:1 << 40) | fixed_point_bce(2^-20).
// Column layout [bi*BLOCK+tid] -> no address sharing between lanes/waves.
// (R7 lesson: fp atomicAdd on LDS lowers to a serial CAS loop -> 104us.
//  Integer ds_add_u64 is native, non-returning, fire-and-forget.)
// ---------------------------------------------------------------------------

__global__ __launch_bounds__(BLOCK) void ghm_pass1(
        const float4* __restrict__ x4, const float4* __restrict__ t4,
        const float* __restrict__ xs, const float* __restrict__ ts,
        float* __restrict__ psum, unsigned int* __restrict__ pcnt,
        int nvec, int total) {
    __shared__ unsigned long long hist[BINS * BLOCK];   // 20 KiB
    const int tid = threadIdx.x;
#pragma unroll
    for (int b = 0; b < BINS; ++b) hist[b * BLOCK + tid] = 0ull;
    __syncthreads();

    const float L2E    = 1.44269504088896f;   // log2(e)
    const float LN2    = 0.69314718055995f;   // ln(2)
    const float QSCALE = 1048576.0f;          // 2^20 fixed-point scale

    auto proc = [&](float xv, float tv) {
        float e   = __builtin_amdgcn_exp2f(-L2E * __builtin_fabsf(xv)); // e^-|x|
        float ope = 1.0f + e;
        float r   = __builtin_amdgcn_rcpf(ope);           // 1/(1+e)
        float sig = (xv >= 0.0f) ? r : e * r;             // stable sigmoid
        float g   = __builtin_fabsf(sig - tv);            // in [0,1]
        int bi = (int)(g * 9.9999f);
        bi = bi > (BINS - 1) ? (BINS - 1) : bi;           // ulp safety clamp
        float l2  = __builtin_amdgcn_logf(ope);           // log2(1+e)
        float bce = __builtin_fmaf(-xv, tv, __builtin_fmaxf(xv, 0.0f));
        bce = __builtin_fmaf(LN2, l2, bce);               // + ln(1+e)
        // round-to-nearest fixed point; bce<=~7 -> q < 2^23 << 2^40
        unsigned int q = (unsigned int)__builtin_fmaf(bce, QSCALE, 0.5f);
        atomicAdd(&hist[bi * BLOCK + tid],
                  (1ull << 40) | (unsigned long long)q);  // ds_add_u64
    };

    const int stride = gridDim.x * BLOCK;
    const int gid0   = blockIdx.x * BLOCK + tid;

    // unroll-2: two independent float4 pairs in flight per iteration
    int i = gid0;
    for (; i + stride < nvec; i += 2 * stride) {
        float4 xa = x4[i];          float4 ta = t4[i];
        float4 xb = x4[i + stride]; float4 tb = t4[i + stride];
        proc(xa.x, ta.x); proc(xa.y, ta.y); proc(xa.z, ta.z); proc(xa.w, ta.w);
        proc(xb.x, tb.x); proc(xb.y, tb.y); proc(xb.z, tb.z); proc(xb.w, tb.w);
    }
    for (; i < nvec; i += stride) {
        float4 xa = x4[i]; float4 ta = t4[i];
        proc(xa.x, ta.x); proc(xa.y, ta.y); proc(xa.z, ta.z); proc(xa.w, ta.w);
    }
    // scalar tail (not hit for this shape; kept for safety)
    for (int j = nvec * 4 + gid0; j < total; j += stride)
        proc(xs[j], ts[j]);

    __syncthreads();

    // Block reduce: packed u64 fields can't overflow at block level
    // (<=4096 elems/block: count < 2^13 at bit 40, sum < 3e10 < 2^40).
    unsigned long long v[BINS];
#pragma unroll
    for (int b = 0; b < BINS; ++b) v[b] = hist[b * BLOCK + tid];
    __syncthreads();                                    // reads done -> reuse

    const int lane = tid & 63;
    const int wid  = tid >> 6;
#pragma unroll
    for (int b = 0; b < BINS; ++b) {
        unsigned long long s = v[b];
#pragma unroll
        for (int off = 32; off > 0; off >>= 1)
            s += __shfl_down(s, off);
        if (lane == 0) hist[wid * BINS + b] = s;
    }
    __syncthreads();
    if (tid < BINS) {
        unsigned long long tot = 0ull;
#pragma unroll
        for (int w = 0; w < BLOCK / 64; ++w) tot += hist[w * BINS + tid];
        unsigned long long sum_fp = tot & ((1ull << 40) - 1ull);
        unsigned int       cntv   = (unsigned int)(tot >> 40);
        psum[(size_t)blockIdx.x * BINS + tid] =
            (float)((double)sum_fp * 9.5367431640625e-7);   // * 2^-20
        pcnt[(size_t)blockIdx.x * BINS + tid] = cntv;
    }
}

// ---------------------------------------------------------------------------
// Pass 2: single strided sweep over partials (10 static accumulators per
// thread), one wave+LDS reduce, beta math as in the reference (fp32).
// ---------------------------------------------------------------------------

__global__ __launch_bounds__(BLOCK) void ghm_pass2(
        const float* __restrict__ psum, const unsigned int* __restrict__ pcnt,
        float* __restrict__ out, int nblocks, float Nf, double inv_total) {
    double       s[BINS];
    unsigned int c[BINS];
#pragma unroll
    for (int b = 0; b < BINS; ++b) { s[b] = 0.0; c[b] = 0u; }

    for (int i = threadIdx.x; i < nblocks; i += BLOCK) {
#pragma unroll
        for (int b = 0; b < BINS; ++b) {
            s[b] += (double)psum[(size_t)i * BINS + b];
            c[b] += pcnt[(size_t)i * BINS + b];
        }
    }

    __shared__ double       ls[BLOCK / 64][BINS];
    __shared__ unsigned int lc[BLOCK / 64][BINS];
    const int lane = threadIdx.x & 63;
    const int wid  = threadIdx.x >> 6;
#pragma unroll
    for (int b = 0; b < BINS; ++b) {
        double       sb = s[b];
        unsigned int cb = c[b];
#pragma unroll
        for (int off = 32; off > 0; off >>= 1) {
            sb += __shfl_down(sb, off);
            cb += __shfl_down(cb, off);
        }
        if (lane == 0) { ls[wid][b] = sb; lc[wid][b] = cb; }
    }
    __syncthreads();

    if (threadIdx.x == 0) {
        double             bin_sum[BINS];
        unsigned long long bin_cnt[BINS];
#pragma unroll
        for (int b = 0; b < BINS; ++b) {
            double ts = 0.0;
            unsigned long long tc = 0;
#pragma unroll
            for (int w = 0; w < BLOCK / 64; ++w) { ts += ls[w][b]; tc += lc[w][b]; }
            bin_sum[b] = ts;
            bin_cnt[b] = tc;
        }
        float nonempty = 0.0f;
#pragma unroll
        for (int b = 0; b < BINS; ++b) nonempty += (bin_cnt[b] > 0) ? 1.0f : 0.0f;
        double acc = 0.0;
#pragma unroll
        for (int b = 0; b < BINS; ++b) {
            float bc   = (float)bin_cnt[b];            // reference keeps fp32
            float gd   = fmaxf(bc * nonempty, 1e-6f);
            float beta = Nf / gd;
            acc += (double)beta * bin_sum[b];
        }
        out[0] = (float)(acc * inv_total);
    }
}

// ---------------------------------------------------------------------------

extern "C" void kernel_launch(void* const* d_in, const int* in_sizes, int n_in,
                              void* d_out, int out_size, void* d_ws, size_t ws_size,
                              hipStream_t stream) {
    const float* x = (const float*)d_in[0];
    const float* t = (const float*)d_in[1];
    const int total = in_sizes[0];          // 1048576 * 16
    const int nvec  = total / 4;
    const int N     = total / 16;           // x.shape[0] (first dim)

    int nblocks = NBLK;
    size_t per_block = (size_t)BINS * (sizeof(float) + sizeof(unsigned int));
    if ((size_t)nblocks * per_block > ws_size) {
        nblocks = (int)(ws_size / per_block);
        if (nblocks < 1) nblocks = 1;
    }

    float*        psum = (float*)d_ws;
    unsigned int* pcnt = (unsigned int*)((char*)d_ws +
                          (size_t)nblocks * BINS * sizeof(float));

    ghm_pass1<<<nblocks, BLOCK, 0, stream>>>(
        (const float4*)x, (const float4*)t, x, t, psum, pcnt, nvec, total);
    ghm_pass2<<<1, BLOCK, 0, stream>>>(
        psum, pcnt, (float*)d_out, nblocks, (float)N, 1.0 / (double)total);
}